// Round 1
// baseline (1178.167 us; speedup 1.0000x reference)
//
#include <hip/hip_runtime.h>
#include <math.h>

#define BB 32768
#define BN 20
#define DD 172
#define TT 100
#define EE 272
#define HD2 136
#define BT 16

// ================= new pipeline constants =================
#define XLD 448      // xbuf row: [attn_out(272) | source(172) | pad(4)]
#define QLD 548      // qkbuf row: [h0: qk(272)+sconst(1)][h1: qk+sconst] = 546, pad 548
#define NQK 546
#define GBM 128
#define GBN 128
#define GBK 64

// =========================================================================
// Generic tiled f32 GEMM:  C[i][n] = act( bias[n] + sum_k A[i][k]*W[n*ldw+k] )
// M = BB (grid.x * 128), N,K runtime. Requires K % 4 == 0, N % 4 == 0 ... N
// only needs the *store guard* granularity of 4 (buffers are padded so the
// float4 store/bias-load beyond logical N stays in-bounds).
// 256 threads, 128x128 tile, BK=64, 8x8 micro-tile (split 4+4 to keep LDS
// reads 2-way-conflict free), 4x4 register-transposed staging so LDS stores
// are b128, XOR-swizzled columns to kill the 8-way store conflict.
// act: 0 none, 1 relu, 2 zero-row-if-inval
// =========================================================================
#define GSWZ(k) ((((k) >> 3) & 7) << 2)

__global__ __launch_bounds__(256, 2)
void gemm_f32(const float* __restrict__ A, int lda,
              const float* __restrict__ W, int ldw,
              const float* __restrict__ bias,
              float* __restrict__ C, int ldc,
              int N, int K, int act, const int* __restrict__ inval)
{
  __shared__ float As[GBK][GBM + 4];
  __shared__ float Ws[GBK][GBN + 4];
  const int t  = threadIdx.x;
  const int bm = blockIdx.x * GBM;
  const int bn = blockIdx.y * GBN;
  const int tx = t & 15, ty = t >> 4;
  const int c4 = (t & 15) * 4;       // k-offset within tile for staging
  const int g4 = (t >> 4) * 4;       // row-group for staging

  float acc[8][8];
#pragma unroll
  for (int i = 0; i < 8; i++)
#pragma unroll
    for (int j = 0; j < 8; j++) acc[i][j] = 0.f;

  for (int kt = 0; kt < K; kt += GBK) {
    const int kg = kt + c4;
    const bool kv = (kg < K);          // K % 4 == 0 -> whole float4 valid
    const int sw = GSWZ(c4);           // same for c4..c4+3

    // ---- stage A: 128 rows x 64 k, 4x4 transpose blocks, b128 LDS stores
#pragma unroll
    for (int p = 0; p < 2; p++) {
      const int m0 = g4 + p * 64;
      float4 v0 = make_float4(0.f,0.f,0.f,0.f), v1 = v0, v2 = v0, v3 = v0;
      if (kv) {
        const float* ap = A + (size_t)(bm + m0) * lda + kg;
        v0 = *(const float4*)(ap);
        v1 = *(const float4*)(ap + lda);
        v2 = *(const float4*)(ap + 2 * (size_t)lda);
        v3 = *(const float4*)(ap + 3 * (size_t)lda);
      }
      const int ms = m0 ^ sw;
      *(float4*)&As[c4 + 0][ms] = make_float4(v0.x, v1.x, v2.x, v3.x);
      *(float4*)&As[c4 + 1][ms] = make_float4(v0.y, v1.y, v2.y, v3.y);
      *(float4*)&As[c4 + 2][ms] = make_float4(v0.z, v1.z, v2.z, v3.z);
      *(float4*)&As[c4 + 3][ms] = make_float4(v0.w, v1.w, v2.w, v3.w);
    }
    // ---- stage W: 128 rows x 64 k (rows = output cols), same scheme
#pragma unroll
    for (int p = 0; p < 2; p++) {
      const int n0 = g4 + p * 64;
      float4 v0 = make_float4(0.f,0.f,0.f,0.f), v1 = v0, v2 = v0, v3 = v0;
      if (kv) {
        const float* wp = W + (size_t)(bn + n0) * ldw + kg;
        if (bn + n0 + 0 < N) v0 = *(const float4*)(wp);
        if (bn + n0 + 1 < N) v1 = *(const float4*)(wp + ldw);
        if (bn + n0 + 2 < N) v2 = *(const float4*)(wp + 2 * (size_t)ldw);
        if (bn + n0 + 3 < N) v3 = *(const float4*)(wp + 3 * (size_t)ldw);
      }
      const int ns = n0 ^ sw;
      *(float4*)&Ws[c4 + 0][ns] = make_float4(v0.x, v1.x, v2.x, v3.x);
      *(float4*)&Ws[c4 + 1][ns] = make_float4(v0.y, v1.y, v2.y, v3.y);
      *(float4*)&Ws[c4 + 2][ns] = make_float4(v0.z, v1.z, v2.z, v3.z);
      *(float4*)&Ws[c4 + 3][ns] = make_float4(v0.w, v1.w, v2.w, v3.w);
    }
    __syncthreads();

#pragma unroll 4
    for (int k = 0; k < GBK; k++) {
      const int s = GSWZ(k);
      const float4 a0 = *(const float4*)&As[k][(ty * 4) ^ s];
      const float4 a1 = *(const float4*)&As[k][(64 + ty * 4) ^ s];
      const float4 b0 = *(const float4*)&Ws[k][(tx * 4) ^ s];
      const float4 b1 = *(const float4*)&Ws[k][(64 + tx * 4) ^ s];
      const float av[8] = {a0.x, a0.y, a0.z, a0.w, a1.x, a1.y, a1.z, a1.w};
      const float bv[8] = {b0.x, b0.y, b0.z, b0.w, b1.x, b1.y, b1.z, b1.w};
#pragma unroll
      for (int i = 0; i < 8; i++)
#pragma unroll
        for (int j = 0; j < 8; j++)
          acc[i][j] = fmaf(av[i], bv[j], acc[i][j]);
    }
    __syncthreads();
  }

  // ---- epilogue ----
#pragma unroll
  for (int i = 0; i < 8; i++) {
    const int row = bm + ((i < 4) ? (ty * 4 + i) : (64 + ty * 4 + i - 4));
    const int zr = (act == 2) ? inval[row] : 0;
#pragma unroll
    for (int jh = 0; jh < 2; jh++) {
      const int n0 = bn + jh * 64 + tx * 4;
      if (n0 < N) {
        const float4 bs = *(const float4*)(bias + n0);
        float4 v = make_float4(acc[i][jh * 4 + 0] + bs.x,
                               acc[i][jh * 4 + 1] + bs.y,
                               acc[i][jh * 4 + 2] + bs.z,
                               acc[i][jh * 4 + 3] + bs.w);
        if (act == 1) {
          v.x = fmaxf(v.x, 0.f); v.y = fmaxf(v.y, 0.f);
          v.z = fmaxf(v.z, 0.f); v.w = fmaxf(v.w, 0.f);
        }
        if (zr) { v.x = 0.f; v.y = 0.f; v.z = 0.f; v.w = 0.f; }
        *(float4*)(C + (size_t)row * ldc + n0) = v;
      }
    }
  }
}

// =========================================================================
// prep 0: qconst[e] = bq[e] + sum_u cos(tb[u]) * wq[e][172+u]
//         cvo[e]    = bo[e] + sum_c bv[c] * wo[e][c]
// =========================================================================
__global__ __launch_bounds__(256)
void kprep0(const float* __restrict__ ipw, const float* __restrict__ ipb,
            const float* __restrict__ opw, const float* __restrict__ opb,
            const float* __restrict__ tbg,
            float* __restrict__ qconst, float* __restrict__ cvo)
{
  for (int e = threadIdx.x; e < EE; e += 256) {
    float s = ipb[e];
    for (int u = 0; u < TT; u++)
      s += cosf(tbg[u]) * ipw[(size_t)e * EE + DD + u];
    qconst[e] = s;
    float s2 = opb[e];
    for (int c = 0; c < EE; c++)
      s2 += ipb[2 * EE + c] * opw[(size_t)e * EE + c];
    cvo[e] = s2;
  }
}

// =========================================================================
// prep 1: folded weights.
//  WQK[n=h*273+j][k<172] = sum_d wq[h*136+d][k] * (j<272 ? wk[h*136+d][j]
//                                                        : bk[h*136+d])
//  cQK[n]                = sum_d qconst[h*136+d] * (same)
//  WVO[e][h*272+j]       = sum_d wv[h*136+d][j] * wo[e][h*136+d]
// =========================================================================
#define NT1 (NQK * DD)          // 93912
#define NT2 (NT1 + NQK)         // 94458
#define NT3 (NT2 + EE * 2 * EE) // 242426

__global__ __launch_bounds__(256)
void kprep1(const float* __restrict__ ipw, const float* __restrict__ ipb,
            const float* __restrict__ opw, const float* __restrict__ qconst,
            float* __restrict__ wqk, float* __restrict__ cqk,
            float* __restrict__ wvo)
{
  for (int idx = blockIdx.x * 256 + threadIdx.x; idx < NT3;
       idx += gridDim.x * 256) {
    if (idx < NT1) {
      const int n = idx / DD, k = idx % DD;
      const int h = n / 273, j = n % 273;
      const float* wa = ipw + (size_t)(h * HD2) * EE + k;     // stride EE over d
      float s = 0.f;
      if (j < EE) {
        const float* wb = ipw + (size_t)(EE + h * HD2) * EE + j;
        for (int d = 0; d < HD2; d++) s += wa[(size_t)d * EE] * wb[(size_t)d * EE];
      } else {
        const float* bb = ipb + EE + h * HD2;
        for (int d = 0; d < HD2; d++) s += wa[(size_t)d * EE] * bb[d];
      }
      wqk[idx] = s;
    } else if (idx < NT2) {
      const int n = idx - NT1;
      const int h = n / 273, j = n % 273;
      const float* qc = qconst + h * HD2;
      float s = 0.f;
      if (j < EE) {
        const float* wb = ipw + (size_t)(EE + h * HD2) * EE + j;
        for (int d = 0; d < HD2; d++) s += qc[d] * wb[(size_t)d * EE];
      } else {
        const float* bb = ipb + EE + h * HD2;
        for (int d = 0; d < HD2; d++) s += qc[d] * bb[d];
      }
      cqk[n] = s;
    } else {
      const int r = idx - NT2;
      const int e = r / (2 * EE), kk = r % (2 * EE);
      const int h = kk / EE, j = kk % EE;
      const float* wv = ipw + (size_t)(2 * EE + h * HD2) * EE + j; // stride EE
      const float* wo = opw + (size_t)e * EE + h * HD2;            // stride 1
      float s = 0.f;
      for (int d = 0; d < HD2; d++) s += wv[(size_t)d * EE] * wo[d];
      wvo[r] = s;
    }
  }
}

// =========================================================================
// source extraction: xbuf[i][272+d] = msg[i][19][d]
// =========================================================================
__global__ __launch_bounds__(256)
void ksrc(const float* __restrict__ msg, float* __restrict__ xbuf)
{
  const int total = BB * DD;
  for (int idx = blockIdx.x * 256 + threadIdx.x; idx < total;
       idx += gridDim.x * 256) {
    const int i = idx / DD, d = idx % DD;
    xbuf[(size_t)i * XLD + EE + d] =
        msg[((size_t)i * BN + (BN - 1)) * DD + d];
  }
}

// =========================================================================
// attention middle: one wave per batch row. Reads msg coalesced (lane = col),
// computes scores (msg-dot + cos-feature-dot), softmax, mbar; writes mbar
// in-place over the qk row (row-local, safe). 4 rows per 256-thread block.
// =========================================================================
__global__ __launch_bounds__(256, 2)
void attn_mid(const float* __restrict__ msg,
              const float* __restrict__ timeb,
              const float* __restrict__ twg,
              const float* __restrict__ tbg,
              float* __restrict__ qkbuf,
              int* __restrict__ inval)
{
  __shared__ float s_red[4][16][41];
  __shared__ float s_sc[4][40];
  const int t = threadIdx.x;
  const int w = t >> 6, l = t & 63;
  const size_t i = (size_t)blockIdx.x * 4 + w;

  // deltas + mask (all lanes redundant; broadcast loads)
  const float* tbr = timeb + i * BN;
  float d[BN];
  unsigned msk = 0;
  const float st = tbr[BN - 1];
#pragma unroll
  for (int n = 0; n < BN; n++) {
    const float v = tbr[n];
    if (v < 0.f) msk |= (1u << n);
    d[n] = v - st;
  }
  const int inv = (msk == ((1u << BN) - 1u)) ? 1 : 0;
  if (inv) msk &= ~1u;

  const float w0 = twg[l], b0 = tbg[l];
  float w1 = 0.f, b1 = 0.f;
  if (l < TT - 64) { w1 = twg[64 + l]; b1 = tbg[64 + l]; }

  float* qkr = qkbuf + i * QLD;
  float qm0[2], qm1[2], qm2[2], qt0[2], qt1[2], sct[2];
#pragma unroll
  for (int h = 0; h < 2; h++) {
    const float* q = qkr + h * 273;
    qm0[h] = q[l];
    qm1[h] = q[64 + l];                          // 64+63 < 172 always
    qm2[h] = (l < DD - 128) ? q[128 + l] : 0.f;  // l < 44
    qt0[h] = q[DD + l];
    qt1[h] = (l < TT - 64) ? q[DD + 64 + l] : 0.f;
    sct[h] = q[272];
  }

  // scores: partial dots, lane owns columns {l, l+64, l+128}
  const float* mrow = msg + i * (size_t)(BN * DD);
  float acc[2][BN];
#pragma unroll
  for (int n = 0; n < BN; n++) { acc[0][n] = 0.f; acc[1][n] = 0.f; }
#pragma unroll
  for (int n = 0; n < BN; n++) {
    const float m0 = mrow[n * DD + l];
    const float m1 = mrow[n * DD + 64 + l];
    const float m2 = (l < DD - 128) ? mrow[n * DD + 128 + l] : 0.f;
    const float c0 = __cosf(d[n] * w0 + b0);
    const float c1 = __cosf(d[n] * w1 + b1);   // garbage for l>=36, qt1=0
    acc[0][n] += m0 * qm0[0] + m1 * qm1[0] + m2 * qm2[0] + c0 * qt0[0] + c1 * qt1[0];
    acc[1][n] += m0 * qm0[1] + m1 * qm1[1] + m2 * qm2[1] + c0 * qt0[1] + c1 * qt1[1];
  }

  // reduce 64 lanes -> 16 via 2 butterfly levels, then LDS transpose-sum
  float* af = &acc[0][0];
#pragma unroll
  for (int x = 0; x < 40; x++) {
    float v = af[x];
    v += __shfl_xor(v, 32);
    v += __shfl_xor(v, 16);
    af[x] = v;
  }
  if (l < 16) {
#pragma unroll
    for (int x = 0; x < 40; x++) s_red[w][l][x] = af[x];
  }
  __syncthreads();
  if (l < 40) {
    float s = 0.f;
#pragma unroll
    for (int q = 0; q < 16; q++) s += s_red[w][q][l];
    const int h = (l >= BN) ? 1 : 0;
    const int n = l - h * BN;
    s += sct[h];
    s *= 0.08574929257125442f;                // 1/sqrt(136)
    if ((msk >> n) & 1u) s = -1e9f;
    s_sc[w][l] = s;
  }
  __syncthreads();

  // broadcast scores; redundant per-lane softmax (all lanes need attn)
  float p[40];
#pragma unroll
  for (int x = 0; x < 40; x += 4) {
    const float4 v4 = *(const float4*)&s_sc[w][x];
    p[x] = v4.x; p[x + 1] = v4.y; p[x + 2] = v4.z; p[x + 3] = v4.w;
  }
#pragma unroll
  for (int h = 0; h < 2; h++) {
    float mx = p[h * BN];
#pragma unroll
    for (int n = 1; n < BN; n++) mx = fmaxf(mx, p[h * BN + n]);
    float sm = 0.f;
#pragma unroll
    for (int n = 0; n < BN; n++) {
      const float e = __expf(p[h * BN + n] - mx);
      p[h * BN + n] = e; sm += e;
    }
    const float is = 1.f / sm;
#pragma unroll
    for (int n = 0; n < BN; n++) p[h * BN + n] *= is;
  }

  // mbar = attn-weighted msgs_un (msg cols re-hit L1; tf recomputed, cheap)
  float a0[2] = {0.f, 0.f}, a1[2] = {0.f, 0.f}, a2[2] = {0.f, 0.f};
  float t0[2] = {0.f, 0.f}, t1[2] = {0.f, 0.f};
#pragma unroll
  for (int n = 0; n < BN; n++) {
    const float m0 = mrow[n * DD + l];
    const float m1 = mrow[n * DD + 64 + l];
    const float m2 = (l < DD - 128) ? mrow[n * DD + 128 + l] : 0.f;
    const float c0 = __cosf(d[n] * w0 + b0);
    const float c1 = __cosf(d[n] * w1 + b1);
#pragma unroll
    for (int h = 0; h < 2; h++) {
      const float at = p[h * BN + n];
      a0[h] = fmaf(at, m0, a0[h]);
      a1[h] = fmaf(at, m1, a1[h]);
      a2[h] = fmaf(at, m2, a2[h]);
      t0[h] = fmaf(at, c0, t0[h]);
      t1[h] = fmaf(at, c1, t1[h]);
    }
  }
  // write mbar[h*272 + j] over the qk row (all qk reads already done)
#pragma unroll
  for (int h = 0; h < 2; h++) {
    float* o = qkr + h * EE;
    o[l] = a0[h];
    o[64 + l] = a1[h];
    if (l < DD - 128) o[128 + l] = a2[h];
    o[DD + l] = t0[h];
    if (l < TT - 64) o[DD + 64 + l] = t1[h];
  }
  if (l == 0) inval[i] = inv;
}

// =========================================================================
// ===================== fallback: previous fused kernel ===================
// =========================================================================
__device__ __forceinline__ void gemm_rowW(
    const float* __restrict__ W, int ldw, int kcol0,
    const float* __restrict__ bias,
    const float* __restrict__ A, int lda,
    int K,
    float* OUT, int ldo, int NO,
    bool accum, int act,
    const int* __restrict__ inval,
    float* __restrict__ gout, int gld,
    int t)
{
  const int eo = t & 63;
  const int i0 = (t >> 6) * 4;
  for (int e = eo; e < NO; e += 128) {
    const int e2 = e + 64;
    const bool has2 = (e2 < NO);
    float acc[4][2];
    const float b1 = (!accum && bias) ? bias[e] : 0.f;
    const float b2 = (!accum && bias && has2) ? bias[e2] : 0.f;
#pragma unroll
    for (int ii = 0; ii < 4; ii++) {
      acc[ii][0] = accum ? OUT[(i0 + ii) * ldo + e] : b1;
      acc[ii][1] = has2 ? (accum ? OUT[(i0 + ii) * ldo + e2] : b2) : 0.f;
    }
    const float* w1 = W + (size_t)e * ldw + kcol0;
    const float* w2 = W + (size_t)e2 * ldw + kcol0;
    for (int k = 0; k < K; k += 4) {
      const float4 wq1 = *(const float4*)(w1 + k);
      float4 wq2 = make_float4(0.f, 0.f, 0.f, 0.f);
      if (has2) wq2 = *(const float4*)(w2 + k);
#pragma unroll
      for (int ii = 0; ii < 4; ii++) {
        const float4 a = *(const float4*)(A + (size_t)(i0 + ii) * lda + k);
        acc[ii][0] += a.x * wq1.x + a.y * wq1.y + a.z * wq1.z + a.w * wq1.w;
        acc[ii][1] += a.x * wq2.x + a.y * wq2.y + a.z * wq2.z + a.w * wq2.w;
      }
    }
#pragma unroll
    for (int ii = 0; ii < 4; ii++) {
      float v1 = acc[ii][0], v2 = acc[ii][1];
      if (act == 1) { v1 = fmaxf(v1, 0.f); v2 = fmaxf(v2, 0.f); }
      else if (act == 2) { if (inval[i0 + ii]) { v1 = 0.f; v2 = 0.f; } }
      if (gout) {
        gout[(i0 + ii) * gld + e] = v1;
        if (has2) gout[(i0 + ii) * gld + e2] = v2;
      } else {
        OUT[(i0 + ii) * ldo + e] = v1;
        if (has2) OUT[(i0 + ii) * ldo + e2] = v2;
      }
    }
  }
}

__device__ __forceinline__ void gemm_colW(
    const float* __restrict__ W, int ldw,
    const float* __restrict__ A, int lda,
    int K,
    float* OUT, int ldo, int NO,
    int t)
{
  const int eo = t & 63;
  const int i0 = (t >> 6) * 4;
  for (int j = eo; j < NO; j += 128) {
    const int j2 = j + 64;
    const bool has2 = (j2 < NO);
    float acc[4][2];
#pragma unroll
    for (int ii = 0; ii < 4; ii++) { acc[ii][0] = 0.f; acc[ii][1] = 0.f; }
    for (int dd = 0; dd < K; dd += 4) {
      const float* wr = W + (size_t)dd * ldw;
      const float w10 = wr[j];
      const float w11 = wr[ldw + j];
      const float w12 = wr[2 * ldw + j];
      const float w13 = wr[3 * ldw + j];
      float w20 = 0.f, w21 = 0.f, w22 = 0.f, w23 = 0.f;
      if (has2) { w20 = wr[j2]; w21 = wr[ldw + j2]; w22 = wr[2 * ldw + j2]; w23 = wr[3 * ldw + j2]; }
#pragma unroll
      for (int ii = 0; ii < 4; ii++) {
        const float4 a = *(const float4*)(A + (size_t)(i0 + ii) * lda + dd);
        acc[ii][0] += a.x * w10 + a.y * w11 + a.z * w12 + a.w * w13;
        acc[ii][1] += a.x * w20 + a.y * w21 + a.z * w22 + a.w * w23;
      }
    }
#pragma unroll
    for (int ii = 0; ii < 4; ii++) {
      OUT[(i0 + ii) * ldo + j] = acc[ii][0];
      if (has2) OUT[(i0 + ii) * ldo + j2] = acc[ii][1];
    }
  }
}

__global__ __launch_bounds__(256, 2)
void attn_msg_agg_fused(const float* __restrict__ msg,
                        const float* __restrict__ timeb,
                        const float* __restrict__ tw_g,
                        const float* __restrict__ tb_g,
                        const float* __restrict__ ipw,
                        const float* __restrict__ ipb,
                        const float* __restrict__ opw,
                        const float* __restrict__ opb,
                        const float* __restrict__ f1w,
                        const float* __restrict__ f1b,
                        const float* __restrict__ f2w,
                        const float* __restrict__ f2b,
                        float* __restrict__ outg)
{
  __shared__ __align__(16) float s_q[BT * EE];
  __shared__ __align__(16) float s_qk[BT * 2 * EE];
  __shared__ __align__(16) float s_attn[BT * 2 * BN];
  __shared__ __align__(16) float s_delta[BT * BN];
  __shared__ __align__(16) float s_tw[TT];
  __shared__ __align__(16) float s_tb[TT];
  __shared__ __align__(16) float s_tfl[TT];
  __shared__ float s_sconst[BT * 2];
  __shared__ unsigned s_mask[BT];
  __shared__ int s_inval[BT];

  const int t = threadIdx.x;
  const int base = blockIdx.x * BT;

  if (t < TT) {
    const float b = tb_g[t];
    s_tw[t] = tw_g[t];
    s_tb[t] = b;
    s_tfl[t] = __cosf(b);
  }
  for (int idx = t; idx < BT * BN; idx += 256)
    s_delta[idx] = timeb[(size_t)base * BN + idx];
  __syncthreads();
  if (t < BT) {
    const float st = s_delta[t * BN + BN - 1];
    unsigned m = 0;
#pragma unroll
    for (int n = 0; n < BN; n++) {
      const float v = s_delta[t * BN + n];
      if (v < 0.f) m |= (1u << n);
      s_delta[t * BN + n] = v - st;
    }
    const int inv = (m == ((1u << BN) - 1u)) ? 1 : 0;
    if (inv) m &= ~1u;
    s_mask[t] = m;
    s_inval[t] = inv;
  }
  __syncthreads();

  const float* srcA = msg + (size_t)base * BN * DD + (size_t)(BN - 1) * DD;
  gemm_rowW(ipw, EE, 0, ipb, srcA, BN * DD, DD, s_q, EE, EE, false, 0, nullptr, nullptr, 0, t);
  gemm_rowW(ipw, EE, DD, nullptr, s_tfl, 0, TT, s_q, EE, EE, true, 0, nullptr, nullptr, 0, t);
  __syncthreads();

  if (t < BT * 2) {
    const int i = t >> 1, h = t & 1;
    const float* qv = s_q + i * EE + h * HD2;
    const float* bk = ipb + EE + h * HD2;
    float s = 0.f;
    for (int dd = 0; dd < HD2; dd++) s += qv[dd] * bk[dd];
    s_sconst[t] = s;
  }
  gemm_colW(ipw + (size_t)EE * EE, EE, s_q, EE, HD2, s_qk, 2 * EE, EE, t);
  gemm_colW(ipw + (size_t)(EE + HD2) * EE, EE, s_q + HD2, EE, HD2, s_qk + EE, 2 * EE, EE, t);
  __syncthreads();

  const float scale = 0.08574929257125442f;
  for (int o = t; o < BT * 2 * BN; o += 256) {
    const int i = o / (2 * BN);
    const int r = o % (2 * BN);
    const int h = r / BN;
    const int n = r % BN;
    const float* mrow = msg + ((size_t)(base + i) * BN + n) * DD;
    const float* qkv = s_qk + i * 2 * EE + h * EE;
    float s = s_sconst[i * 2 + h];
    for (int dd = 0; dd < DD; dd += 4) {
      const float4 m4 = *(const float4*)(mrow + dd);
      const float4 q4 = *(const float4*)(qkv + dd);
      s += m4.x * q4.x + m4.y * q4.y + m4.z * q4.z + m4.w * q4.w;
    }
    const float del = s_delta[i * BN + n];
    const float* qkt = qkv + DD;
    for (int u = 0; u < TT; u++)
      s += __cosf(del * s_tw[u] + s_tb[u]) * qkt[u];
    const bool masked = (s_mask[i] >> n) & 1u;
    s_attn[o] = masked ? -1e9f : s * scale;
  }
  __syncthreads();

  if (t < BT * 2) {
    float* sc = s_attn + t * BN;
    float m = -3.4e38f;
#pragma unroll
    for (int n = 0; n < BN; n++) m = fmaxf(m, sc[n]);
    float sum = 0.f;
#pragma unroll
    for (int n = 0; n < BN; n++) { const float e = __expf(sc[n] - m); sc[n] = e; sum += e; }
    const float inv = 1.f / sum;
#pragma unroll
    for (int n = 0; n < BN; n++) sc[n] *= inv;
  }
  __syncthreads();

  for (int o = t; o < BT * 2 * EE; o += 256) {
    const int i = o / (2 * EE);
    const int r = o % (2 * EE);
    const int h = r / EE;
    const int j = r % EE;
    const float* at = s_attn + (i * 2 + h) * BN;
    float acc = 0.f;
    if (j < DD) {
      const float* mp = msg + (size_t)(base + i) * BN * DD + j;
#pragma unroll
      for (int n = 0; n < BN; n++) acc += at[n] * mp[n * DD];
    } else {
      const int u = j - DD;
      const float ww = s_tw[u], bb = s_tb[u];
#pragma unroll
      for (int n = 0; n < BN; n++) acc += at[n] * __cosf(s_delta[i * BN + n] * ww + bb);
    }
    s_qk[o] = acc;
  }
  __syncthreads();

  gemm_rowW(ipw + (size_t)(2 * EE) * EE, EE, 0, ipb + 2 * EE,
            s_qk, 2 * EE, EE, s_q, EE, HD2, false, 0, nullptr, nullptr, 0, t);
  gemm_rowW(ipw + (size_t)(2 * EE + HD2) * EE, EE, 0, ipb + 2 * EE + HD2,
            s_qk + EE, 2 * EE, EE, s_q + HD2, EE, HD2, false, 0, nullptr, nullptr, 0, t);
  __syncthreads();

  gemm_rowW(opw, EE, 0, opb, s_q, EE, EE, s_qk, 2 * EE, EE, false, 2, s_inval, nullptr, 0, t);
  __syncthreads();

  gemm_rowW(f1w, EE + DD, 0, f1b, s_qk, 2 * EE, EE, s_q, EE, DD, false, 0, nullptr, nullptr, 0, t);
  gemm_rowW(f1w, EE + DD, EE, nullptr, srcA, BN * DD, DD, s_q, EE, DD, true, 1, nullptr, nullptr, 0, t);
  __syncthreads();

  gemm_rowW(f2w, DD, 0, f2b, s_q, EE, DD, nullptr, 0, DD, false, 0, nullptr,
            outg + (size_t)base * DD, DD, t);
}

// =========================================================================
extern "C" void kernel_launch(void* const* d_in, const int* in_sizes, int n_in,
                              void* d_out, int out_size, void* d_ws, size_t ws_size,
                              hipStream_t stream) {
  const float* msg  = (const float*)d_in[0];
  const float* tb   = (const float*)d_in[1];
  // d_in[2] (memory) is unused by the reference
  const float* tw_g = (const float*)d_in[3];
  const float* tb_g = (const float*)d_in[4];
  const float* ipw  = (const float*)d_in[5];
  const float* ipb  = (const float*)d_in[6];
  const float* opw  = (const float*)d_in[7];
  const float* opb  = (const float*)d_in[8];
  const float* f1w  = (const float*)d_in[9];
  const float* f1b  = (const float*)d_in[10];
  const float* f2w  = (const float*)d_in[11];
  const float* f2b  = (const float*)d_in[12];
  float* outg = (float*)d_out;

  // workspace layout (floats)
  const size_t F_X   = 0;
  const size_t F_QK  = F_X   + (size_t)BB * XLD;
  const size_t F_WQK = F_QK  + (size_t)BB * QLD;
  const size_t F_CQK = F_WQK + (size_t)NQK * DD;
  const size_t F_WVO = F_CQK + 548;
  const size_t F_CVO = F_WVO + (size_t)EE * 2 * EE;
  const size_t F_QC  = F_CVO + EE;
  const size_t F_INV = F_QC  + EE;
  const size_t NEEDF = F_INV + BB;

  if (ws_size >= NEEDF * sizeof(float)) {
    float* ws    = (float*)d_ws;
    float* xbuf  = ws + F_X;
    float* qkb   = ws + F_QK;
    float* wqk   = ws + F_WQK;
    float* cqk   = ws + F_CQK;
    float* wvo   = ws + F_WVO;
    float* cvo   = ws + F_CVO;
    float* qc    = ws + F_QC;
    int*   inval = (int*)(ws + F_INV);

    hipLaunchKernelGGL(kprep0, dim3(1), dim3(256), 0, stream,
                       ipw, ipb, opw, opb, tb_g, qc, cvo);
    hipLaunchKernelGGL(kprep1, dim3(512), dim3(256), 0, stream,
                       ipw, ipb, opw, qc, wqk, cqk, wvo);
    hipLaunchKernelGGL(ksrc, dim3(2048), dim3(256), 0, stream, msg, xbuf);
    // qk = src @ WQK + cQK   (M=B, N=546, K=172)
    hipLaunchKernelGGL(gemm_f32, dim3(BB / GBM, 5), dim3(256), 0, stream,
                       xbuf + EE, XLD, wqk, DD, cqk, qkb, QLD,
                       NQK, DD, 0, (const int*)nullptr);
    // scores / softmax / mbar (mbar overwrites qk rows in place)
    hipLaunchKernelGGL(attn_mid, dim3(BB / 4), dim3(256), 0, stream,
                       msg, tb, tw_g, tb_g, qkb, inval);
    // attn_out = mbar @ WVO + cVO, zero-if-invalid -> xbuf[:, 0:272]
    hipLaunchKernelGGL(gemm_f32, dim3(BB / GBM, 3), dim3(256), 0, stream,
                       qkb, QLD, wvo, 2 * EE, cvo, xbuf, XLD,
                       EE, 2 * EE, 2, inval);
    // h1 = relu([attn_out, src] @ fc1^T + b1) -> qkb (reused, ld=172)
    hipLaunchKernelGGL(gemm_f32, dim3(BB / GBM, 2), dim3(256), 0, stream,
                       xbuf, XLD, f1w, EE + DD, f1b, qkb, DD,
                       DD, EE + DD, 1, (const int*)nullptr);
    // out = h1 @ fc2^T + b2 -> global
    hipLaunchKernelGGL(gemm_f32, dim3(BB / GBM, 2), dim3(256), 0, stream,
                       qkb, DD, f2w, DD, f2b, outg, DD,
                       DD, DD, 0, (const int*)nullptr);
  } else {
    // workspace too small: previous verified fused kernel
    dim3 grid(BB / BT), block(256);
    hipLaunchKernelGGL(attn_msg_agg_fused, grid, block, 0, stream,
                       msg, tb, tw_g, tb_g, ipw, ipb, opw, opb,
                       f1w, f1b, f2w, f2b, outg);
  }
}

// Round 2
// 1075.270 us; speedup vs baseline: 1.0957x; 1.0957x over previous
//
#include <hip/hip_runtime.h>
#include <math.h>

#define BB 32768
#define BN 20
#define DD 172
#define TT 100
#define EE 272
#define HD2 136
#define BT 16

// ================= pipeline constants =================
// xbuf row (ld 728): [src(172) | flag(1) | pad0(3) | mbar(544)] = K-region 720,
// where [176..723] first holds qk (546+2 pad) written by gemm_qk, then mbar
// (544) is written in-place over it by attn_mid (row-local, reads-before-writes).
#define XLD2 728
#define KMO  720
#define QOFF 176
#define NQK  546
#define HLD  176
#define GBM 128
#define GBK 64

#define GSWZ(k) ((((k) >> 3) & 7) << 2)

// =========================================================================
// Tiled f32 GEMM:  C[i][n] = act( bias[n] + sum_k A[i][k]*W[n*ldw+k] )
// 256 threads, 128 x (PW*64) tile, BK=64, 8 x (4*PW) micro-tile.
// Reg-staged with early prefetch of the next k-tile (issue loads before FMAs).
// K % 4 == 0 required; N guarded at granularity 4 (pads in buffers).
// act: 0 none, 1 relu
// =========================================================================
template<int PW>
__device__ __forceinline__ void g_fetch(
    const float* __restrict__ A, int lda,
    const float* __restrict__ W, int ldw,
    int N, int K, int bm, int bn, int kt, int c4, int g4,
    float4 ra[2][4], float4 rw[PW][4])
{
  const int kg = kt + c4;
  const bool kv = (kg < K);
#pragma unroll
  for (int p = 0; p < 2; p++) {
    if (kv) {
      const float* ap = A + (size_t)(bm + g4 + p * 64) * lda + kg;
      ra[p][0] = *(const float4*)(ap);
      ra[p][1] = *(const float4*)(ap + lda);
      ra[p][2] = *(const float4*)(ap + 2 * (size_t)lda);
      ra[p][3] = *(const float4*)(ap + 3 * (size_t)lda);
    } else {
      ra[p][0] = ra[p][1] = ra[p][2] = ra[p][3] = make_float4(0.f, 0.f, 0.f, 0.f);
    }
  }
#pragma unroll
  for (int p = 0; p < PW; p++) {
    const int n0 = g4 + p * 64;
    rw[p][0] = rw[p][1] = rw[p][2] = rw[p][3] = make_float4(0.f, 0.f, 0.f, 0.f);
    if (kv) {
      const float* wp = W + (size_t)(bn + n0) * ldw + kg;
      if (bn + n0 + 0 < N) rw[p][0] = *(const float4*)(wp);
      if (bn + n0 + 1 < N) rw[p][1] = *(const float4*)(wp + ldw);
      if (bn + n0 + 2 < N) rw[p][2] = *(const float4*)(wp + 2 * (size_t)ldw);
      if (bn + n0 + 3 < N) rw[p][3] = *(const float4*)(wp + 3 * (size_t)ldw);
    }
  }
}

template<int PW>
__global__ __launch_bounds__(256, 2)
void gemm_f32(const float* __restrict__ A, int lda,
              const float* __restrict__ W, int ldw,
              const float* __restrict__ bias,
              float* __restrict__ C, int ldc,
              int N, int K, int act)
{
  __shared__ float As[GBK][GBM + 4];
  __shared__ float Ws[GBK][PW * 64 + 4];
  const int t  = threadIdx.x;
  const int bm = blockIdx.x * GBM;
  const int bn = blockIdx.y * (PW * 64);
  const int tx = t & 15, ty = t >> 4;
  const int c4 = (t & 15) * 4;
  const int g4 = (t >> 4) * 4;
  const int sw0 = GSWZ(c4);

  float acc[8][4 * PW];
#pragma unroll
  for (int i = 0; i < 8; i++)
#pragma unroll
    for (int j = 0; j < 4 * PW; j++) acc[i][j] = 0.f;

  float4 ra[2][4], rw[PW][4];
  g_fetch<PW>(A, lda, W, ldw, N, K, bm, bn, 0, c4, g4, ra, rw);

  for (int kt = 0; kt < K; kt += GBK) {
    // store staged regs -> LDS (4x4 transposed, XOR-swizzled)
#pragma unroll
    for (int p = 0; p < 2; p++) {
      const int ms = (g4 + p * 64) ^ sw0;
      *(float4*)&As[c4 + 0][ms] = make_float4(ra[p][0].x, ra[p][1].x, ra[p][2].x, ra[p][3].x);
      *(float4*)&As[c4 + 1][ms] = make_float4(ra[p][0].y, ra[p][1].y, ra[p][2].y, ra[p][3].y);
      *(float4*)&As[c4 + 2][ms] = make_float4(ra[p][0].z, ra[p][1].z, ra[p][2].z, ra[p][3].z);
      *(float4*)&As[c4 + 3][ms] = make_float4(ra[p][0].w, ra[p][1].w, ra[p][2].w, ra[p][3].w);
    }
#pragma unroll
    for (int p = 0; p < PW; p++) {
      const int ns = (g4 + p * 64) ^ sw0;
      *(float4*)&Ws[c4 + 0][ns] = make_float4(rw[p][0].x, rw[p][1].x, rw[p][2].x, rw[p][3].x);
      *(float4*)&Ws[c4 + 1][ns] = make_float4(rw[p][0].y, rw[p][1].y, rw[p][2].y, rw[p][3].y);
      *(float4*)&Ws[c4 + 2][ns] = make_float4(rw[p][0].z, rw[p][1].z, rw[p][2].z, rw[p][3].z);
      *(float4*)&Ws[c4 + 3][ns] = make_float4(rw[p][0].w, rw[p][1].w, rw[p][2].w, rw[p][3].w);
    }
    __syncthreads();

    // prefetch next k-tile early (overlaps with FMAs below)
    if (kt + GBK < K)
      g_fetch<PW>(A, lda, W, ldw, N, K, bm, bn, kt + GBK, c4, g4, ra, rw);

#pragma unroll 4
    for (int k = 0; k < GBK; k++) {
      const int s = GSWZ(k);
      const float4 a0 = *(const float4*)&As[k][(ty * 4) ^ s];
      const float4 a1 = *(const float4*)&As[k][(64 + ty * 4) ^ s];
      const float av[8] = {a0.x, a0.y, a0.z, a0.w, a1.x, a1.y, a1.z, a1.w};
      float bv[4 * PW];
      const float4 b0 = *(const float4*)&Ws[k][(tx * 4) ^ s];
      bv[0] = b0.x; bv[1] = b0.y; bv[2] = b0.z; bv[3] = b0.w;
      if constexpr (PW == 2) {
        const float4 b1 = *(const float4*)&Ws[k][(64 + tx * 4) ^ s];
        bv[4] = b1.x; bv[5] = b1.y; bv[6] = b1.z; bv[7] = b1.w;
      }
#pragma unroll
      for (int i = 0; i < 8; i++)
#pragma unroll
        for (int j = 0; j < 4 * PW; j++)
          acc[i][j] = fmaf(av[i], bv[j], acc[i][j]);
    }
    __syncthreads();
  }

  // ---- epilogue ----
#pragma unroll
  for (int i = 0; i < 8; i++) {
    const int row = bm + ((i < 4) ? (ty * 4 + i) : (64 + ty * 4 + i - 4));
#pragma unroll
    for (int jh = 0; jh < PW; jh++) {
      const int n0 = bn + jh * 64 + tx * 4;
      if (n0 < N) {
        const float4 bs = *(const float4*)(bias + n0);
        float4 v = make_float4(acc[i][jh * 4 + 0] + bs.x,
                               acc[i][jh * 4 + 1] + bs.y,
                               acc[i][jh * 4 + 2] + bs.z,
                               acc[i][jh * 4 + 3] + bs.w);
        if (act == 1) {
          v.x = fmaxf(v.x, 0.f); v.y = fmaxf(v.y, 0.f);
          v.z = fmaxf(v.z, 0.f); v.w = fmaxf(v.w, 0.f);
        }
        *(float4*)(C + (size_t)row * ldc + n0) = v;
      }
    }
  }
}

// =========================================================================
// prep A: qconst[e] = bq[e] + sum_u cos(tb[u]) * wq[e][172+u]
// =========================================================================
__global__ __launch_bounds__(256)
void kprepA(const float* __restrict__ ipw, const float* __restrict__ ipb,
            const float* __restrict__ tbg, float* __restrict__ qconst)
{
  for (int e = threadIdx.x; e < EE; e += 256) {
    float s = ipb[e];
    for (int u = 0; u < TT; u++)
      s += cosf(tbg[u]) * ipw[(size_t)e * EE + DD + u];
    qconst[e] = s;
  }
}

// =========================================================================
// prep B: WQK (546 x 172), cQK (546, +2 zero pad), T = W1a @ Wo (172 x 272)
//  WQK[n=h*273+j][k] = sum_d wq[h*136+d][k] * (j<272 ? wk[h*136+d][j]
//                                                    : bk[h*136+d])
//  T[o][c] = sum_e f1w[o][e] * opw[e][c]
// =========================================================================
#define PB0 (NQK * DD)            // 93912
#define PB1 (PB0 + NQK)           // 94458
#define PB2 (PB1 + DD * EE)       // 141242

__global__ __launch_bounds__(256)
void kprepB(const float* __restrict__ ipw, const float* __restrict__ ipb,
            const float* __restrict__ opw, const float* __restrict__ f1w,
            const float* __restrict__ qconst,
            float* __restrict__ wqk, float* __restrict__ cqk,
            float* __restrict__ Tm)
{
  if (blockIdx.x == 0 && threadIdx.x < 2) cqk[NQK + threadIdx.x] = 0.f;
  for (int idx = blockIdx.x * 256 + threadIdx.x; idx < PB2;
       idx += gridDim.x * 256) {
    if (idx < PB0) {
      const int n = idx / DD, k = idx % DD;
      const int h = n / 273, j = n % 273;
      const float* wa = ipw + (size_t)(h * HD2) * EE + k;
      float s = 0.f;
      if (j < EE) {
        const float* wb = ipw + (size_t)(EE + h * HD2) * EE + j;
        for (int d = 0; d < HD2; d++) s += wa[(size_t)d * EE] * wb[(size_t)d * EE];
      } else {
        const float* bb = ipb + EE + h * HD2;
        for (int d = 0; d < HD2; d++) s += wa[(size_t)d * EE] * bb[d];
      }
      wqk[idx] = s;
    } else if (idx < PB1) {
      const int n = idx - PB0;
      const int h = n / 273, j = n % 273;
      const float* qc = qconst + h * HD2;
      float s = 0.f;
      if (j < EE) {
        const float* wb = ipw + (size_t)(EE + h * HD2) * EE + j;
        for (int d = 0; d < HD2; d++) s += qc[d] * wb[(size_t)d * EE];
      } else {
        const float* bb = ipb + EE + h * HD2;
        for (int d = 0; d < HD2; d++) s += qc[d] * bb[d];
      }
      cqk[n] = s;
    } else {
      const int r = idx - PB1;
      const int o = r / EE, c = r % EE;
      const float* fa = f1w + (size_t)o * (EE + DD);
      const float* wb = opw + c;
      float s = 0.f;
      for (int e = 0; e < EE; e++) s += fa[e] * wb[(size_t)e * EE];
      Tm[r] = s;
    }
  }
}

// =========================================================================
// prep C: WMOF (172 x 720) over K-cols [src(172) | flag(1) | pad(3) | mbar(544)]
//  kk <  172 : f1w[o][272+kk]                          (src path W1b)
//  kk == 172 : sum_e f1w[o][e]*bo[e] + sum_c T[o][c]*bv[c]   (valid-only const)
//  kk in 173..175 : 0
//  kk >= 176 : j2=kk-176, h=j2/272, j=j2%272:
//              sum_d T[o][h*136+d] * wv[h*136+d][j]    (mbar -> fc1 path)
// =========================================================================
#define PCN (DD * KMO)            // 123840

__global__ __launch_bounds__(256)
void kprepC(const float* __restrict__ ipw, const float* __restrict__ ipb,
            const float* __restrict__ opb, const float* __restrict__ f1w,
            const float* __restrict__ Tm, float* __restrict__ wmof)
{
  for (int idx = blockIdx.x * 256 + threadIdx.x; idx < PCN;
       idx += gridDim.x * 256) {
    const int o = idx / KMO, kk = idx % KMO;
    float s;
    if (kk < DD) {
      s = f1w[(size_t)o * (EE + DD) + EE + kk];
    } else if (kk == DD) {
      const float* fa = f1w + (size_t)o * (EE + DD);
      const float* Tr = Tm + (size_t)o * EE;
      s = 0.f;
      for (int e = 0; e < EE; e++) s += fa[e] * opb[e];
      for (int c = 0; c < EE; c++) s += Tr[c] * ipb[2 * EE + c];
    } else if (kk < QOFF) {
      s = 0.f;
    } else {
      const int j2 = kk - QOFF;
      const int h = j2 / EE, j = j2 % EE;
      const float* Tr = Tm + (size_t)o * EE + h * HD2;
      const float* wv = ipw + (size_t)(2 * EE + h * HD2) * EE + j;
      s = 0.f;
      for (int d = 0; d < HD2; d++) s += Tr[d] * wv[(size_t)d * EE];
    }
    wmof[idx] = s;
  }
}

// =========================================================================
// source extraction: xbuf[i][d] = msg[i][19][d]   (cols 0..171 of K-region)
// =========================================================================
__global__ __launch_bounds__(256)
void ksrc(const float* __restrict__ msg, float* __restrict__ xbuf)
{
  const int total = BB * DD;
  for (int idx = blockIdx.x * 256 + threadIdx.x; idx < total;
       idx += gridDim.x * 256) {
    const int i = idx / DD, d = idx % DD;
    xbuf[(size_t)i * XLD2 + d] = msg[((size_t)i * BN + (BN - 1)) * DD + d];
  }
}

// =========================================================================
// attention middle: one wave per batch row. Reads qk (at xrow+176), computes
// scores/softmax/mbar; writes mbar in-place over qk, zeroed if invalid;
// writes flag col (172) and zero pads (173..175).
// =========================================================================
__global__ __launch_bounds__(256, 2)
void attn_mid(const float* __restrict__ msg,
              const float* __restrict__ timeb,
              const float* __restrict__ twg,
              const float* __restrict__ tbg,
              float* __restrict__ xbuf)
{
  __shared__ float s_red[4][16][41];
  __shared__ float s_sc[4][40];
  const int t = threadIdx.x;
  const int w = t >> 6, l = t & 63;
  const size_t i = (size_t)blockIdx.x * 4 + w;

  // deltas + mask (all lanes redundant; broadcast loads)
  const float* tbr = timeb + i * BN;
  float d[BN];
  unsigned msk = 0;
  const float st = tbr[BN - 1];
#pragma unroll
  for (int n = 0; n < BN; n++) {
    const float v = tbr[n];
    if (v < 0.f) msk |= (1u << n);
    d[n] = v - st;
  }
  const int inv = (msk == ((1u << BN) - 1u)) ? 1 : 0;
  if (inv) msk &= ~1u;
  const float vf = inv ? 0.f : 1.f;

  const float w0 = twg[l], b0 = tbg[l];
  float w1 = 0.f, b1 = 0.f;
  if (l < TT - 64) { w1 = twg[64 + l]; b1 = tbg[64 + l]; }

  float* xrow = xbuf + i * XLD2;
  float* qkr = xrow + QOFF;
  float qm0[2], qm1[2], qm2[2], qt0[2], qt1[2], sct[2];
#pragma unroll
  for (int h = 0; h < 2; h++) {
    const float* q = qkr + h * 273;
    qm0[h] = q[l];
    qm1[h] = q[64 + l];                          // 64+63 < 172
    qm2[h] = (l < DD - 128) ? q[128 + l] : 0.f;  // l < 44
    qt0[h] = q[DD + l];
    qt1[h] = (l < TT - 64) ? q[DD + 64 + l] : 0.f;
    sct[h] = q[272];
  }

  // scores: partial dots, lane owns columns {l, l+64, l+128}
  const float* mrow = msg + i * (size_t)(BN * DD);
  float acc[2][BN];
#pragma unroll
  for (int n = 0; n < BN; n++) { acc[0][n] = 0.f; acc[1][n] = 0.f; }
#pragma unroll
  for (int n = 0; n < BN; n++) {
    const float m0 = mrow[n * DD + l];
    const float m1 = mrow[n * DD + 64 + l];
    const float m2 = (l < DD - 128) ? mrow[n * DD + 128 + l] : 0.f;
    const float c0 = __cosf(d[n] * w0 + b0);
    const float c1 = __cosf(d[n] * w1 + b1);   // garbage for l>=36, qt1=0
    acc[0][n] += m0 * qm0[0] + m1 * qm1[0] + m2 * qm2[0] + c0 * qt0[0] + c1 * qt1[0];
    acc[1][n] += m0 * qm0[1] + m1 * qm1[1] + m2 * qm2[1] + c0 * qt0[1] + c1 * qt1[1];
  }

  // reduce 64 lanes -> 16 via 2 butterfly levels, then LDS transpose-sum
  float* af = &acc[0][0];
#pragma unroll
  for (int x = 0; x < 40; x++) {
    float v = af[x];
    v += __shfl_xor(v, 32);
    v += __shfl_xor(v, 16);
    af[x] = v;
  }
  if (l < 16) {
#pragma unroll
    for (int x = 0; x < 40; x++) s_red[w][l][x] = af[x];
  }
  __syncthreads();
  if (l < 40) {
    float s = 0.f;
#pragma unroll
    for (int q = 0; q < 16; q++) s += s_red[w][q][l];
    const int h = (l >= BN) ? 1 : 0;
    const int n = l - h * BN;
    s += sct[h];
    s *= 0.08574929257125442f;                // 1/sqrt(136)
    if ((msk >> n) & 1u) s = -1e9f;
    s_sc[w][l] = s;
  }
  __syncthreads();

  // broadcast scores; redundant per-lane softmax (all lanes need attn)
  float p[40];
#pragma unroll
  for (int x = 0; x < 40; x += 4) {
    const float4 v4 = *(const float4*)&s_sc[w][x];
    p[x] = v4.x; p[x + 1] = v4.y; p[x + 2] = v4.z; p[x + 3] = v4.w;
  }
#pragma unroll
  for (int h = 0; h < 2; h++) {
    float mx = p[h * BN];
#pragma unroll
    for (int n = 1; n < BN; n++) mx = fmaxf(mx, p[h * BN + n]);
    float sm = 0.f;
#pragma unroll
    for (int n = 0; n < BN; n++) {
      const float e = __expf(p[h * BN + n] - mx);
      p[h * BN + n] = e; sm += e;
    }
    const float is = 1.f / sm;
#pragma unroll
    for (int n = 0; n < BN; n++) p[h * BN + n] *= is;
  }

  // mbar = attn-weighted msgs_un (msg cols re-hit L1/L2; tf recomputed)
  float a0[2] = {0.f, 0.f}, a1[2] = {0.f, 0.f}, a2[2] = {0.f, 0.f};
  float t0[2] = {0.f, 0.f}, t1[2] = {0.f, 0.f};
#pragma unroll
  for (int n = 0; n < BN; n++) {
    const float m0 = mrow[n * DD + l];
    const float m1 = mrow[n * DD + 64 + l];
    const float m2 = (l < DD - 128) ? mrow[n * DD + 128 + l] : 0.f;
    const float c0 = __cosf(d[n] * w0 + b0);
    const float c1 = __cosf(d[n] * w1 + b1);
#pragma unroll
    for (int h = 0; h < 2; h++) {
      const float at = p[h * BN + n];
      a0[h] = fmaf(at, m0, a0[h]);
      a1[h] = fmaf(at, m1, a1[h]);
      a2[h] = fmaf(at, m2, a2[h]);
      t0[h] = fmaf(at, c0, t0[h]);
      t1[h] = fmaf(at, c1, t1[h]);
    }
  }
  // write mbar (zeroed if invalid) over the qk region; all reads done above
#pragma unroll
  for (int h = 0; h < 2; h++) {
    float* o = qkr + h * EE;
    o[l] = a0[h] * vf;
    o[64 + l] = a1[h] * vf;
    if (l < DD - 128) o[128 + l] = a2[h] * vf;
    o[DD + l] = t0[h] * vf;
    if (l < TT - 64) o[DD + 64 + l] = t1[h] * vf;
  }
  if (l == 0) {
    xrow[DD] = vf;            // flag column (172)
    xrow[DD + 1] = 0.f;       // pads 173..175
    xrow[DD + 2] = 0.f;
    xrow[DD + 3] = 0.f;
  }
}

// =========================================================================
// ===================== fallback: previous fused kernel ===================
// =========================================================================
__device__ __forceinline__ void gemm_rowW(
    const float* __restrict__ W, int ldw, int kcol0,
    const float* __restrict__ bias,
    const float* __restrict__ A, int lda,
    int K,
    float* OUT, int ldo, int NO,
    bool accum, int act,
    const int* __restrict__ inval,
    float* __restrict__ gout, int gld,
    int t)
{
  const int eo = t & 63;
  const int i0 = (t >> 6) * 4;
  for (int e = eo; e < NO; e += 128) {
    const int e2 = e + 64;
    const bool has2 = (e2 < NO);
    float acc[4][2];
    const float b1 = (!accum && bias) ? bias[e] : 0.f;
    const float b2 = (!accum && bias && has2) ? bias[e2] : 0.f;
#pragma unroll
    for (int ii = 0; ii < 4; ii++) {
      acc[ii][0] = accum ? OUT[(i0 + ii) * ldo + e] : b1;
      acc[ii][1] = has2 ? (accum ? OUT[(i0 + ii) * ldo + e2] : b2) : 0.f;
    }
    const float* w1 = W + (size_t)e * ldw + kcol0;
    const float* w2 = W + (size_t)e2 * ldw + kcol0;
    for (int k = 0; k < K; k += 4) {
      const float4 wq1 = *(const float4*)(w1 + k);
      float4 wq2 = make_float4(0.f, 0.f, 0.f, 0.f);
      if (has2) wq2 = *(const float4*)(w2 + k);
#pragma unroll
      for (int ii = 0; ii < 4; ii++) {
        const float4 a = *(const float4*)(A + (size_t)(i0 + ii) * lda + k);
        acc[ii][0] += a.x * wq1.x + a.y * wq1.y + a.z * wq1.z + a.w * wq1.w;
        acc[ii][1] += a.x * wq2.x + a.y * wq2.y + a.z * wq2.z + a.w * wq2.w;
      }
    }
#pragma unroll
    for (int ii = 0; ii < 4; ii++) {
      float v1 = acc[ii][0], v2 = acc[ii][1];
      if (act == 1) { v1 = fmaxf(v1, 0.f); v2 = fmaxf(v2, 0.f); }
      else if (act == 2) { if (inval[i0 + ii]) { v1 = 0.f; v2 = 0.f; } }
      if (gout) {
        gout[(i0 + ii) * gld + e] = v1;
        if (has2) gout[(i0 + ii) * gld + e2] = v2;
      } else {
        OUT[(i0 + ii) * ldo + e] = v1;
        if (has2) OUT[(i0 + ii) * ldo + e2] = v2;
      }
    }
  }
}

__device__ __forceinline__ void gemm_colW(
    const float* __restrict__ W, int ldw,
    const float* __restrict__ A, int lda,
    int K,
    float* OUT, int ldo, int NO,
    int t)
{
  const int eo = t & 63;
  const int i0 = (t >> 6) * 4;
  for (int j = eo; j < NO; j += 128) {
    const int j2 = j + 64;
    const bool has2 = (j2 < NO);
    float acc[4][2];
#pragma unroll
    for (int ii = 0; ii < 4; ii++) { acc[ii][0] = 0.f; acc[ii][1] = 0.f; }
    for (int dd = 0; dd < K; dd += 4) {
      const float* wr = W + (size_t)dd * ldw;
      const float w10 = wr[j];
      const float w11 = wr[ldw + j];
      const float w12 = wr[2 * ldw + j];
      const float w13 = wr[3 * ldw + j];
      float w20 = 0.f, w21 = 0.f, w22 = 0.f, w23 = 0.f;
      if (has2) { w20 = wr[j2]; w21 = wr[ldw + j2]; w22 = wr[2 * ldw + j2]; w23 = wr[3 * ldw + j2]; }
#pragma unroll
      for (int ii = 0; ii < 4; ii++) {
        const float4 a = *(const float4*)(A + (size_t)(i0 + ii) * lda + dd);
        acc[ii][0] += a.x * w10 + a.y * w11 + a.z * w12 + a.w * w13;
        acc[ii][1] += a.x * w20 + a.y * w21 + a.z * w22 + a.w * w23;
      }
    }
#pragma unroll
    for (int ii = 0; ii < 4; ii++) {
      OUT[(i0 + ii) * ldo + j] = acc[ii][0];
      if (has2) OUT[(i0 + ii) * ldo + j2] = acc[ii][1];
    }
  }
}

__global__ __launch_bounds__(256, 2)
void attn_msg_agg_fused(const float* __restrict__ msg,
                        const float* __restrict__ timeb,
                        const float* __restrict__ tw_g,
                        const float* __restrict__ tb_g,
                        const float* __restrict__ ipw,
                        const float* __restrict__ ipb,
                        const float* __restrict__ opw,
                        const float* __restrict__ opb,
                        const float* __restrict__ f1w,
                        const float* __restrict__ f1b,
                        const float* __restrict__ f2w,
                        const float* __restrict__ f2b,
                        float* __restrict__ outg)
{
  __shared__ __align__(16) float s_q[BT * EE];
  __shared__ __align__(16) float s_qk[BT * 2 * EE];
  __shared__ __align__(16) float s_attn[BT * 2 * BN];
  __shared__ __align__(16) float s_delta[BT * BN];
  __shared__ __align__(16) float s_tw[TT];
  __shared__ __align__(16) float s_tb[TT];
  __shared__ __align__(16) float s_tfl[TT];
  __shared__ float s_sconst[BT * 2];
  __shared__ unsigned s_mask[BT];
  __shared__ int s_inval[BT];

  const int t = threadIdx.x;
  const int base = blockIdx.x * BT;

  if (t < TT) {
    const float b = tb_g[t];
    s_tw[t] = tw_g[t];
    s_tb[t] = b;
    s_tfl[t] = __cosf(b);
  }
  for (int idx = t; idx < BT * BN; idx += 256)
    s_delta[idx] = timeb[(size_t)base * BN + idx];
  __syncthreads();
  if (t < BT) {
    const float st = s_delta[t * BN + BN - 1];
    unsigned m = 0;
#pragma unroll
    for (int n = 0; n < BN; n++) {
      const float v = s_delta[t * BN + n];
      if (v < 0.f) m |= (1u << n);
      s_delta[t * BN + n] = v - st;
    }
    const int inv = (m == ((1u << BN) - 1u)) ? 1 : 0;
    if (inv) m &= ~1u;
    s_mask[t] = m;
    s_inval[t] = inv;
  }
  __syncthreads();

  const float* srcA = msg + (size_t)base * BN * DD + (size_t)(BN - 1) * DD;
  gemm_rowW(ipw, EE, 0, ipb, srcA, BN * DD, DD, s_q, EE, EE, false, 0, nullptr, nullptr, 0, t);
  gemm_rowW(ipw, EE, DD, nullptr, s_tfl, 0, TT, s_q, EE, EE, true, 0, nullptr, nullptr, 0, t);
  __syncthreads();

  if (t < BT * 2) {
    const int i = t >> 1, h = t & 1;
    const float* qv = s_q + i * EE + h * HD2;
    const float* bk = ipb + EE + h * HD2;
    float s = 0.f;
    for (int dd = 0; dd < HD2; dd++) s += qv[dd] * bk[dd];
    s_sconst[t] = s;
  }
  gemm_colW(ipw + (size_t)EE * EE, EE, s_q, EE, HD2, s_qk, 2 * EE, EE, t);
  gemm_colW(ipw + (size_t)(EE + HD2) * EE, EE, s_q + HD2, EE, HD2, s_qk + EE, 2 * EE, EE, t);
  __syncthreads();

  const float scale = 0.08574929257125442f;
  for (int o = t; o < BT * 2 * BN; o += 256) {
    const int i = o / (2 * BN);
    const int r = o % (2 * BN);
    const int h = r / BN;
    const int n = r % BN;
    const float* mrow = msg + ((size_t)(base + i) * BN + n) * DD;
    const float* qkv = s_qk + i * 2 * EE + h * EE;
    float s = s_sconst[i * 2 + h];
    for (int dd = 0; dd < DD; dd += 4) {
      const float4 m4 = *(const float4*)(mrow + dd);
      const float4 q4 = *(const float4*)(qkv + dd);
      s += m4.x * q4.x + m4.y * q4.y + m4.z * q4.z + m4.w * q4.w;
    }
    const float del = s_delta[i * BN + n];
    const float* qkt = qkv + DD;
    for (int u = 0; u < TT; u++)
      s += __cosf(del * s_tw[u] + s_tb[u]) * qkt[u];
    const bool masked = (s_mask[i] >> n) & 1u;
    s_attn[o] = masked ? -1e9f : s * scale;
  }
  __syncthreads();

  if (t < BT * 2) {
    float* sc = s_attn + t * BN;
    float m = -3.4e38f;
#pragma unroll
    for (int n = 0; n < BN; n++) m = fmaxf(m, sc[n]);
    float sum = 0.f;
#pragma unroll
    for (int n = 0; n < BN; n++) { const float e = __expf(sc[n] - m); sc[n] = e; sum += e; }
    const float inv = 1.f / sum;
#pragma unroll
    for (int n = 0; n < BN; n++) sc[n] *= inv;
  }
  __syncthreads();

  for (int o = t; o < BT * 2 * EE; o += 256) {
    const int i = o / (2 * EE);
    const int r = o % (2 * EE);
    const int h = r / EE;
    const int j = r % EE;
    const float* at = s_attn + (i * 2 + h) * BN;
    float acc = 0.f;
    if (j < DD) {
      const float* mp = msg + (size_t)(base + i) * BN * DD + j;
#pragma unroll
      for (int n = 0; n < BN; n++) acc += at[n] * mp[n * DD];
    } else {
      const int u = j - DD;
      const float ww = s_tw[u], bb = s_tb[u];
#pragma unroll
      for (int n = 0; n < BN; n++) acc += at[n] * __cosf(s_delta[i * BN + n] * ww + bb);
    }
    s_qk[o] = acc;
  }
  __syncthreads();

  gemm_rowW(ipw + (size_t)(2 * EE) * EE, EE, 0, ipb + 2 * EE,
            s_qk, 2 * EE, EE, s_q, EE, HD2, false, 0, nullptr, nullptr, 0, t);
  gemm_rowW(ipw + (size_t)(2 * EE + HD2) * EE, EE, 0, ipb + 2 * EE + HD2,
            s_qk + EE, 2 * EE, EE, s_q + HD2, EE, HD2, false, 0, nullptr, nullptr, 0, t);
  __syncthreads();

  gemm_rowW(opw, EE, 0, opb, s_q, EE, EE, s_qk, 2 * EE, EE, false, 2, s_inval, nullptr, 0, t);
  __syncthreads();

  gemm_rowW(f1w, EE + DD, 0, f1b, s_qk, 2 * EE, EE, s_q, EE, DD, false, 0, nullptr, nullptr, 0, t);
  gemm_rowW(f1w, EE + DD, EE, nullptr, srcA, BN * DD, DD, s_q, EE, DD, true, 1, nullptr, nullptr, 0, t);
  __syncthreads();

  gemm_rowW(f2w, DD, 0, f2b, s_q, EE, DD, nullptr, 0, DD, false, 0, nullptr,
            outg + (size_t)base * DD, DD, t);
}

// =========================================================================
extern "C" void kernel_launch(void* const* d_in, const int* in_sizes, int n_in,
                              void* d_out, int out_size, void* d_ws, size_t ws_size,
                              hipStream_t stream) {
  const float* msg  = (const float*)d_in[0];
  const float* tb   = (const float*)d_in[1];
  // d_in[2] (memory) is unused by the reference
  const float* tw_g = (const float*)d_in[3];
  const float* tb_g = (const float*)d_in[4];
  const float* ipw  = (const float*)d_in[5];
  const float* ipb  = (const float*)d_in[6];
  const float* opw  = (const float*)d_in[7];
  const float* opb  = (const float*)d_in[8];
  const float* f1w  = (const float*)d_in[9];
  const float* f1b  = (const float*)d_in[10];
  const float* f2w  = (const float*)d_in[11];
  const float* f2b  = (const float*)d_in[12];
  float* outg = (float*)d_out;

  // workspace layout (floats)
  const size_t F_X    = 0;
  const size_t F_H    = F_X    + (size_t)BB * XLD2;   // 23,855,104
  const size_t F_WQK  = F_H    + (size_t)BB * HLD;    // + 5,767,168
  const size_t F_CQK  = F_WQK  + (size_t)NQK * DD;    // + 93,912
  const size_t F_T    = F_CQK  + 548;
  const size_t F_WMOF = F_T    + (size_t)DD * EE;     // + 46,784
  const size_t F_QC   = F_WMOF + (size_t)DD * KMO;    // + 123,840
  const size_t NEEDF  = F_QC   + EE;                  // ~29.9M floats ~120 MB

  if (ws_size >= NEEDF * sizeof(float)) {
    float* ws   = (float*)d_ws;
    float* xbuf = ws + F_X;
    float* hbuf = ws + F_H;
    float* wqk  = ws + F_WQK;
    float* cqk  = ws + F_CQK;
    float* Tm   = ws + F_T;
    float* wmof = ws + F_WMOF;
    float* qc   = ws + F_QC;

    hipLaunchKernelGGL(kprepA, dim3(1), dim3(256), 0, stream,
                       ipw, ipb, tb_g, qc);
    hipLaunchKernelGGL(kprepB, dim3(256), dim3(256), 0, stream,
                       ipw, ipb, opw, f1w, qc, wqk, cqk, Tm);
    hipLaunchKernelGGL(kprepC, dim3(256), dim3(256), 0, stream,
                       ipw, ipb, opb, f1w, Tm, wmof);
    hipLaunchKernelGGL(ksrc, dim3(2048), dim3(256), 0, stream, msg, xbuf);
    // qk = src @ WQK + cQK  (M=B, N=546, K=172) -> xbuf cols [176..723]
    hipLaunchKernelGGL(gemm_f32<2>, dim3(BB / GBM, 5), dim3(256), 0, stream,
                       xbuf, XLD2, wqk, DD, cqk, xbuf + QOFF, XLD2,
                       NQK, DD, 0);
    // scores / softmax / mbar (mbar overwrites qk in place; flag col written)
    hipLaunchKernelGGL(attn_mid, dim3(BB / 4), dim3(256), 0, stream,
                       msg, tb, tw_g, tb_g, xbuf);
    // h1 = relu([src|flag|mbar] @ WMOF^T + b1)  (N=172, K=720) -> hbuf
    hipLaunchKernelGGL(gemm_f32<1>, dim3(BB / GBM, 3), dim3(256), 0, stream,
                       xbuf, XLD2, wmof, KMO, f1b, hbuf, HLD,
                       DD, KMO, 1);
    // out = h1 @ fc2^T + b2  (N=172, K=172)
    hipLaunchKernelGGL(gemm_f32<1>, dim3(BB / GBM, 3), dim3(256), 0, stream,
                       hbuf, HLD, f2w, DD, f2b, outg, DD,
                       DD, DD, 0);
  } else {
    // workspace too small: previous verified fused kernel
    dim3 grid(BB / BT), block(256);
    hipLaunchKernelGGL(attn_msg_agg_fused, grid, block, 0, stream,
                       msg, tb, tw_g, tb_g, ipw, ipb, opw, opb,
                       f1w, f1b, f2w, f2b, outg);
  }
}